// Round 1
// baseline (29590.515 us; speedup 1.0000x reference)
//
#include <hip/hip_runtime.h>
#include <cmath>

namespace {
constexpr int B    = 256;
constexpr int T    = 1000;
constexpr int H    = 256;
constexpr int DIN  = 64;
constexpr int DOUT = 64;
constexpr int NC   = 10;
constexpr int KPAD = 260;          // 257 padded up to multiple of 4
constexpr int N257 = KPAD * H;     // 66560 elements
constexpr int N256 = H * H;        // 65536 elements
}

__device__ __forceinline__ unsigned short f32_to_bf16(float x) {
  unsigned int u = __float_as_uint(x);
  u = (u + 0x7FFFu + ((u >> 16) & 1u)) >> 16;   // round-to-nearest-even
  return (unsigned short)u;
}
__device__ __forceinline__ float bf16_to_f32(unsigned short v) {
  return __uint_as_float(((unsigned int)v) << 16);
}

// Pack the 6 recurrent weight matrices into d_ws as TRANSPOSED bf16:
// layout [k][h] so that lane h reads consecutive addresses (coalesced).
__global__ void pack_weights(const float* __restrict__ Win, const float* __restrict__ Wn,
                             const float* __restrict__ Wf1, const float* __restrict__ Wf2,
                             const float* __restrict__ Wg1, const float* __restrict__ Wg2,
                             unsigned short* __restrict__ ws) {
  int idx = blockIdx.x * blockDim.x + threadIdx.x;
  int stride = gridDim.x * blockDim.x;
  unsigned short* WinT = ws;
  unsigned short* WnT  = WinT + N257;
  unsigned short* Wf1T = WnT  + N257;
  unsigned short* Wf2T = Wf1T + N256;
  unsigned short* Wg1T = Wf2T + N256;
  unsigned short* Wg2T = Wg1T + N256;
  for (int i = idx; i < N257; i += stride) {
    int k = i >> 8, h = i & 255;
    WinT[i] = f32_to_bf16(k < 257 ? Win[h * 257 + k] : 0.f);
    WnT[i]  = f32_to_bf16(k < 257 ? Wn [h * 257 + k] : 0.f);
  }
  for (int i = idx; i < N256; i += stride) {
    int k = i >> 8, h = i & 255;
    Wf1T[i] = f32_to_bf16(Wf1[h * 256 + k]);
    Wf2T[i] = f32_to_bf16(Wf2[h * 256 + k]);
    Wg1T[i] = f32_to_bf16(Wg1[h * 256 + k]);
    Wg2T[i] = f32_to_bf16(Wg2[h * 256 + k]);
  }
}

// out[h] = sum_k x[k] * Wt[k][h], x in LDS (float4 reads), Wt bf16 [k][h].
__device__ __forceinline__ float dotq(const float* __restrict__ x,
                                      const unsigned short* __restrict__ Wt,
                                      int h, int quads) {
  float acc = 0.f;
  const float4* x4 = (const float4*)x;
#pragma unroll 4
  for (int q = 0; q < quads; ++q) {
    float4 xv = x4[q];
    const unsigned short* wp = Wt + q * (4 * H) + h;
    acc += xv.x * bf16_to_f32(wp[0]);
    acc += xv.y * bf16_to_f32(wp[H]);
    acc += xv.z * bf16_to_f32(wp[2 * H]);
    acc += xv.w * bf16_to_f32(wp[3 * H]);
  }
  return acc;
}

// One workgroup per batch row; thread h owns state feature y[h] in a register.
__global__ void __launch_bounds__(256, 1)
sde_scan(const float* __restrict__ coeffs, const float* __restrict__ times,
         const int* __restrict__ mask, const float* __restrict__ noise,
         const float* __restrict__ b_in,
         const float* __restrict__ bf1, const float* __restrict__ bf2,
         const float* __restrict__ bn,
         const float* __restrict__ bg1, const float* __restrict__ bg2,
         const float* __restrict__ W0, const float* __restrict__ b0,
         const float* __restrict__ Wd, const float* __restrict__ bd,
         const float* __restrict__ Wc, const float* __restrict__ bc,
         const unsigned short* __restrict__ wpack,
         float* __restrict__ pred, float* __restrict__ logits) {
  const int b   = blockIdx.x;
  const int tid = threadIdx.x;
  const int h   = tid;

  const unsigned short* WinT = wpack;
  const unsigned short* WnT  = WinT + N257;
  const unsigned short* Wf1T = WnT  + N257;
  const unsigned short* Wf2T = Wf1T + N256;
  const unsigned short* Wg1T = Wf2T + N256;
  const unsigned short* Wg2T = Wg1T + N256;

  __shared__ __align__(16) float ty[KPAD];
  __shared__ __align__(16) float bufA[H];
  __shared__ __align__(16) float bufB[H];
  __shared__ float red[256];
  __shared__ unsigned short ldsWd[H * DOUT];  // [k][j] bf16
  __shared__ unsigned short ldsWc[H * NC];    // [k][j] bf16
  __shared__ int s_last;

  // ---- sequence length from mask ----
  int cnt = 0;
  for (int i = tid; i < T; i += 256) cnt += mask[b * T + i];
  red[tid] = (float)cnt;
  if (tid < 3) ty[257 + tid] = 0.f;          // zero-pad ty tail (K 257->260)
  __syncthreads();
  if (tid == 0) {
    float s = 0.f;
    for (int i = 0; i < 256; ++i) s += red[i];
    s_last = (int)s - 1;
  }
  // ---- stage Wd^T, Wc^T into LDS as bf16 ----
  for (int i = tid; i < H * DOUT; i += 256) {
    int j = i & 63, k = i >> 6;
    ldsWd[k * DOUT + j] = f32_to_bf16(Wd[j * H + k]);
  }
  for (int i = tid; i < H * NC; i += 256) {
    int k = i / NC, j = i - k * NC;
    ldsWc[i] = f32_to_bf16(Wc[j * H + k]);
  }

  const float vb_in = b_in[h], vbf1 = bf1[h], vbf2 = bf2[h];
  const float vbn   = bn[h],   vbg1 = bg1[h], vbg2 = bg2[h];

  // ---- y0 = x0 @ W0^T + b0 ----
  if (tid < DIN) bufA[tid] = coeffs[(size_t)b * (T - 1) * (4 * DIN) + tid];
  __syncthreads();
  float y = b0[h];
#pragma unroll 8
  for (int k = 0; k < DIN; ++k) y += bufA[k] * W0[h * DIN + k];

  __syncthreads();
  bufA[h] = y;
  __syncthreads();

  // ---- predicted[b][0][:] from y0 ----
  {
    int j = tid & 63, q = tid >> 6;
    float p = 0.f;
    for (int k = q * 64; k < q * 64 + 64; ++k)
      p += bufA[k] * bf16_to_f32(ldsWd[k * DOUT + j]);
    red[tid] = p;
    __syncthreads();
    if (tid < DOUT)
      pred[(size_t)b * T * DOUT + tid] =
          bd[tid] + red[tid] + red[64 + tid] + red[128 + tid] + red[192 + tid];
  }
  if (s_last == 0) {
    __syncthreads();
    int j = tid & 63, q = tid >> 6;
    if (j < NC) {
      float p = 0.f;
      for (int k = q * 64; k < q * 64 + 64; ++k)
        p += bufA[k] * bf16_to_f32(ldsWc[k * NC + j]);
      red[q * 16 + j] = p;
    }
    __syncthreads();
    if (tid < NC)
      logits[b * NC + tid] =
          bc[tid] + red[tid] + red[16 + tid] + red[32 + tid] + red[48 + tid];
  }

  // ---- main scan: 999 Euler-Maruyama steps ----
  for (int st = 0; st < T - 1; ++st) {
    float tcur = times[st];
    float dt   = times[st + 1] - tcur;
    float sdt  = sqrtf(dt);

    ty[1 + h] = y;
    if (tid == 0) ty[0] = tcur;
    __syncthreads();

    float yf = vb_in + dotq(ty, WinT, h, KPAD / 4);
    float yg = vbn   + dotq(ty, WnT,  h, KPAD / 4);
    __syncthreads();
    bufA[h] = yf; bufB[h] = yg;
    __syncthreads();

    float u = vbf1 + dotq(bufA, Wf1T, h, H / 4);
    float w = vbg1 + dotq(bufB, Wg1T, h, H / 4);
    float vv = 0.909f * u / (1.f + expf(-u));   // lipswish
    float ss = 0.909f * w / (1.f + expf(-w));
    __syncthreads();
    bufA[h] = vv; bufB[h] = ss;
    __syncthreads();

    float f = vbf2 + dotq(bufA, Wf2T, h, H / 4);
    float g = vbg2 + dotq(bufB, Wg2T, h, H / 4);
    float eps = noise[((size_t)st * B + b) * H + h];
    y += f * dt + g * (sdt * eps);

    __syncthreads();
    bufA[h] = y;
    __syncthreads();

    // predicted[b][st+1][:] = y @ Wd^T + bd   (4-way K split over waves)
    {
      int j = tid & 63, q = tid >> 6;
      float p = 0.f;
      for (int k = q * 64; k < q * 64 + 64; ++k)
        p += bufA[k] * bf16_to_f32(ldsWd[k * DOUT + j]);
      red[tid] = p;
      __syncthreads();
      if (tid < DOUT)
        pred[((size_t)b * T + (st + 1)) * DOUT + tid] =
            bd[tid] + red[tid] + red[64 + tid] + red[128 + tid] + red[192 + tid];
    }
    if (st + 1 == s_last) {
      __syncthreads();
      int j = tid & 63, q = tid >> 6;
      if (j < NC) {
        float p = 0.f;
        for (int k = q * 64; k < q * 64 + 64; ++k)
          p += bufA[k] * bf16_to_f32(ldsWc[k * NC + j]);
        red[q * 16 + j] = p;
      }
      __syncthreads();
      if (tid < NC)
        logits[b * NC + tid] =
            bc[tid] + red[tid] + red[16 + tid] + red[32 + tid] + red[48 + tid];
    }
  }
}

extern "C" void kernel_launch(void* const* d_in, const int* in_sizes, int n_in,
                              void* d_out, int out_size, void* d_ws, size_t ws_size,
                              hipStream_t stream) {
  const float* coeffs = (const float*)d_in[0];
  const float* times  = (const float*)d_in[1];
  const int*   mask   = (const int*)d_in[2];
  const float* noise  = (const float*)d_in[3];
  const float* W_in   = (const float*)d_in[4];
  const float* b_in   = (const float*)d_in[5];
  const float* Wf1    = (const float*)d_in[6];
  const float* bf1    = (const float*)d_in[7];
  const float* Wf2    = (const float*)d_in[8];
  const float* bf2    = (const float*)d_in[9];
  const float* Wn     = (const float*)d_in[10];
  const float* bn     = (const float*)d_in[11];
  const float* Wg1    = (const float*)d_in[12];
  const float* bg1    = (const float*)d_in[13];
  const float* Wg2    = (const float*)d_in[14];
  const float* bg2    = (const float*)d_in[15];
  const float* W0     = (const float*)d_in[16];
  const float* b0     = (const float*)d_in[17];
  const float* Wd     = (const float*)d_in[18];
  const float* bd     = (const float*)d_in[19];
  const float* Wc     = (const float*)d_in[20];
  const float* bc     = (const float*)d_in[21];

  unsigned short* wpack = (unsigned short*)d_ws;  // ~772 KB used
  float* out    = (float*)d_out;
  float* pred   = out;                              // (B, T, DOUT)
  float* logits = out + (size_t)B * T * DOUT;       // (B, NC)

  hipLaunchKernelGGL(pack_weights, dim3(256), dim3(256), 0, stream,
                     W_in, Wn, Wf1, Wf2, Wg1, Wg2, wpack);
  hipLaunchKernelGGL(sde_scan, dim3(B), dim3(256), 0, stream,
                     coeffs, times, mask, noise, b_in, bf1, bf2, bn, bg1, bg2,
                     W0, b0, Wd, bd, Wc, bc, wpack, pred, logits);
}

// Round 2
// 18702.016 us; speedup vs baseline: 1.5822x; 1.5822x over previous
//
#include <hip/hip_runtime.h>
#include <cmath>

namespace {
constexpr int B    = 256;
constexpr int T    = 1000;
constexpr int H    = 256;
constexpr int DIN  = 64;
constexpr int NC   = 10;
constexpr int BT   = 16;    // batch rows per WG
constexpr int NWG  = B / BT;      // 16 workgroups
// packed fragment regions, in bf16 elements (each NT16 region: 8 ksl x 16 nt x 64 lane x 8 = 65536)
constexpr int REG_SZ   = 65536;
constexpr int OFF_WIN  = 0;
constexpr int OFF_WN   = 1 * REG_SZ;
constexpr int OFF_WF1  = 2 * REG_SZ;
constexpr int OFF_WG1  = 3 * REG_SZ;
constexpr int OFF_WF2  = 4 * REG_SZ;
constexpr int OFF_WG2  = 5 * REG_SZ;
constexpr int OFF_WD   = 6 * REG_SZ;           // 8 ksl x 4 nt x 64 x 8 = 16384
constexpr int TOTAL_PK = OFF_WD + 16384;       // 409600 bf16 = 800 KB
}

typedef __attribute__((ext_vector_type(8))) short bf16x8;
typedef __attribute__((ext_vector_type(4))) float f32x4;
#define MFMA16(a, b, c) __builtin_amdgcn_mfma_f32_16x16x32_bf16(a, b, c, 0, 0, 0)

__device__ __forceinline__ unsigned short f32_to_bf16(float x) {
  unsigned int u = __float_as_uint(x);
  u = (u + 0x7FFFu + ((u >> 16) & 1u)) >> 16;   // RNE
  return (unsigned short)u;
}

// Fragment-major pack: block (s, nt) holds B-fragment for k-slice s, n-tile nt:
// elem[lane][j] = W[n][k],  n = 16*nt + (lane&15),  k = 32*s + 8*(lane>>4) + j.
__global__ void pack_frags(const float* __restrict__ Win, const float* __restrict__ Wn,
                           const float* __restrict__ Wf1, const float* __restrict__ Wg1,
                           const float* __restrict__ Wf2, const float* __restrict__ Wg2,
                           const float* __restrict__ Wd, unsigned short* __restrict__ pk) {
  int i = blockIdx.x * blockDim.x + threadIdx.x;
  if (i >= TOTAL_PK) return;
  if (i < OFF_WD) {
    int r = i / REG_SZ, idx = i - r * REG_SZ;
    int j = idx & 7, lane = (idx >> 3) & 63, nt = (idx >> 9) & 15, s = idx >> 13;
    int n = nt * 16 + (lane & 15);
    int k = 32 * s + 8 * (lane >> 4) + j;
    float v;
    if (r == 0)      v = Win[n * 257 + 1 + k];   // skip time col (folded into bias)
    else if (r == 1) v = Wn [n * 257 + 1 + k];
    else if (r == 2) v = Wf1[n * 256 + k];
    else if (r == 3) v = Wg1[n * 256 + k];
    else if (r == 4) v = Wf2[n * 256 + k];
    else             v = Wg2[n * 256 + k];
    pk[i] = f32_to_bf16(v);
  } else {
    int idx = i - OFF_WD;
    int j = idx & 7, lane = (idx >> 3) & 63, nt = (idx >> 9) & 3, s = idx >> 11;
    int n = nt * 16 + (lane & 15);
    int k = 32 * s + 8 * (lane >> 4) + j;
    pk[i] = f32_to_bf16(Wd[n * 256 + k]);
  }
}

// 16 WGs x 512 threads (8 waves). Wave w owns output n-columns [32w, 32w+32).
__global__ void __launch_bounds__(512, 2)
sde_mfma(const float* __restrict__ coeffs, const float* __restrict__ times,
         const int* __restrict__ mask, const float* __restrict__ noise,
         const float* __restrict__ b_in, const float* __restrict__ bf1,
         const float* __restrict__ bf2, const float* __restrict__ bn,
         const float* __restrict__ bg1, const float* __restrict__ bg2,
         const float* __restrict__ W_in, const float* __restrict__ Wn,
         const float* __restrict__ W0, const float* __restrict__ b0p,
         const float* __restrict__ bd, const float* __restrict__ Wc,
         const float* __restrict__ bc,
         const unsigned short* __restrict__ wpack,
         float* __restrict__ pred, float* __restrict__ logits) {
  const int tid  = threadIdx.x;
  const int lane = tid & 63;
  const int w    = tid >> 6;          // wave 0..7
  const int c    = lane & 15;         // col within tile
  const int q4   = lane >> 4;         // quad
  const int rb   = blockIdx.x * BT;   // batch row base

  __shared__ __align__(16) short yA [8 * 64 * 8];
  __shared__ __align__(16) short yfA[8 * 64 * 8];
  __shared__ __align__(16) short ygA[8 * 64 * 8];
  __shared__ __align__(16) short uA [8 * 64 * 8];
  __shared__ __align__(16) short wAA[8 * 64 * 8];
  __shared__ float zfin[BT * H];
  __shared__ float ybuf0[BT * H];
  __shared__ float x0buf[BT * DIN];
  __shared__ int   lastS[BT];

  const bf16x8* pk   = (const bf16x8*)wpack;     // 16 B fragment units
  const bf16x8* pWin = pk + (OFF_WIN >> 3);
  const bf16x8* pWn  = pk + (OFF_WN  >> 3);
  const bf16x8* pWf1 = pk + (OFF_WF1 >> 3);
  const bf16x8* pWg1 = pk + (OFF_WG1 >> 3);
  const bf16x8* pWf2 = pk + (OFF_WF2 >> 3);
  const bf16x8* pWg2 = pk + (OFF_WG2 >> 3);
  const bf16x8* pWd  = pk + (OFF_WD  >> 3);
  const bf16x8* yAv  = (const bf16x8*)yA;
  const bf16x8* yfAv = (const bf16x8*)yfA;
  const bf16x8* ygAv = (const bf16x8*)ygA;
  const bf16x8* uAv  = (const bf16x8*)uA;
  const bf16x8* wAv  = (const bf16x8*)wAA;

  // scatter one value into A-fragment layout: slot(m, k): s=k>>5, q=(k&31)>>3, j=k&7
  auto scat = [&](short* buf, float v, int n, int m) {
    int s = n >> 5, off = n & 31, q = off >> 3, j = off & 7;
    buf[(s * 64 + q * 16 + m) * 8 + j] = (short)f32_to_bf16(v);
  };

  // ---- init: sequence lengths ----
  if (tid < BT) lastS[tid] = 0;
  __syncthreads();
  {
    int m = tid >> 5, sl = tid & 31;
    int cnt = 0;
    for (int i = sl; i < T; i += 32) cnt += mask[(rb + m) * T + i];
    atomicAdd(&lastS[m], cnt);
  }
  for (int i = tid; i < BT * DIN; i += 512) {
    int m = i >> 6, k = i & 63;
    x0buf[i] = coeffs[(size_t)(rb + m) * (T - 1) * (4 * DIN) + k];
  }
  __syncthreads();
  if (tid < BT) lastS[tid] -= 1;
  __syncthreads();

  // ---- y0 = x0 @ W0^T + b0 (scalar, one-time) ----
  for (int o = tid; o < BT * H; o += 512) {
    int m = o >> 8, n = o & 255;
    float acc = b0p[n];
#pragma unroll 8
    for (int k = 0; k < DIN; ++k) acc += x0buf[m * DIN + k] * W0[n * DIN + k];
    ybuf0[o] = acc;
  }
  __syncthreads();

  // ---- per-lane constants ----
  const int n0 = 32 * w + c, n1 = n0 + 16;
  const float binf0 = b_in[n0], binf1 = b_in[n1];
  const float bing0 = bn[n0],   bing1 = bn[n1];
  const float w0f0  = W_in[n0 * 257], w0f1 = W_in[n1 * 257];
  const float w0g0  = Wn[n0 * 257],   w0g1 = Wn[n1 * 257];
  const float bf1v0 = bf1[n0], bf1v1 = bf1[n1];
  const float bg1v0 = bg1[n0], bg1v1 = bg1[n1];
  const float bf2v0 = bf2[n0], bf2v1 = bf2[n1];
  const float bg2v0 = bg2[n0], bg2v1 = bg2[n1];
  const int   np    = w * 16 + c;                      // pred col (waves 0-3)
  const float bdv   = (w < 4) ? bd[np] : 0.f;
  int lst[4];
#pragma unroll
  for (int r = 0; r < 4; ++r) lst[r] = lastS[q4 * 4 + r];

  // ---- y state into registers (C-layout) + yA frags + zfin(last==0) ----
  float yr[2][4];
#pragma unroll
  for (int tt = 0; tt < 2; ++tt)
#pragma unroll
    for (int r = 0; r < 4; ++r) {
      int m = q4 * 4 + r, n = 32 * w + 16 * tt + c;
      float v = ybuf0[m * H + n];
      yr[tt][r] = v;
      if (lst[r] == 0) zfin[m * H + n] = v;
      scat(yA, v, n, m);
    }
  __syncthreads();

  // ---- pred[:, 0, :] ----
  if (w < 4) {
    f32x4 acc = (f32x4){0.f, 0.f, 0.f, 0.f};
#pragma unroll
    for (int s = 0; s < 8; ++s)
      acc = MFMA16(yAv[s * 64 + lane], pWd[(s * 4 + w) * 64 + lane], acc);
#pragma unroll
    for (int r = 0; r < 4; ++r) {
      int m = q4 * 4 + r;
      pred[((size_t)(rb + m) * T + 0) * 64 + np] = acc[r] + bdv;
    }
  }

  // ---- main scan ----
  for (int st = 0; st < T - 1; ++st) {
    float tcur = times[st];
    float dtv  = times[st + 1] - tcur;
    float sdt  = sqrtf(dtv);

    // prefetch noise for this step (used at the update, far below)
    float ep[2][4];
#pragma unroll
    for (int tt = 0; tt < 2; ++tt)
#pragma unroll
      for (int r = 0; r < 4; ++r) {
        int m = q4 * 4 + r, n = 32 * w + 16 * tt + c;
        ep[tt][r] = noise[((size_t)st * B + rb + m) * H + n];
      }

    // ---- stage 1: yf = y@Win', yg = y@Wn' ----
    f32x4 af0 = (f32x4){0.f,0.f,0.f,0.f}, af1 = af0, ag0 = af0, ag1 = af0;
#pragma unroll
    for (int s = 0; s < 8; ++s) {
      bf16x8 a = yAv[s * 64 + lane];
      af0 = MFMA16(a, pWin[(s * 16 + 2 * w    ) * 64 + lane], af0);
      af1 = MFMA16(a, pWin[(s * 16 + 2 * w + 1) * 64 + lane], af1);
      ag0 = MFMA16(a, pWn [(s * 16 + 2 * w    ) * 64 + lane], ag0);
      ag1 = MFMA16(a, pWn [(s * 16 + 2 * w + 1) * 64 + lane], ag1);
    }
#pragma unroll
    for (int r = 0; r < 4; ++r) {
      int m = q4 * 4 + r;
      scat(yfA, af0[r] + binf0 + tcur * w0f0, n0, m);
      scat(yfA, af1[r] + binf1 + tcur * w0f1, n1, m);
      scat(ygA, ag0[r] + bing0 + tcur * w0g0, n0, m);
      scat(ygA, ag1[r] + bing1 + tcur * w0g1, n1, m);
    }
    __syncthreads();

    // ---- stage 2: u = lipswish(yf@Wf1 + bf1), w2 = lipswish(yg@Wg1 + bg1) ----
    f32x4 uc0 = (f32x4){0.f,0.f,0.f,0.f}, uc1 = uc0, wc0 = uc0, wc1 = uc0;
#pragma unroll
    for (int s = 0; s < 8; ++s) {
      bf16x8 a1 = yfAv[s * 64 + lane];
      bf16x8 a2 = ygAv[s * 64 + lane];
      uc0 = MFMA16(a1, pWf1[(s * 16 + 2 * w    ) * 64 + lane], uc0);
      uc1 = MFMA16(a1, pWf1[(s * 16 + 2 * w + 1) * 64 + lane], uc1);
      wc0 = MFMA16(a2, pWg1[(s * 16 + 2 * w    ) * 64 + lane], wc0);
      wc1 = MFMA16(a2, pWg1[(s * 16 + 2 * w + 1) * 64 + lane], wc1);
    }
#pragma unroll
    for (int r = 0; r < 4; ++r) {
      int m = q4 * 4 + r;
      float x0v = uc0[r] + bf1v0;
      float x1v = uc1[r] + bf1v1;
      float x2v = wc0[r] + bg1v0;
      float x3v = wc1[r] + bg1v1;
      scat(uA,  0.909f * x0v / (1.f + __expf(-x0v)), n0, m);
      scat(uA,  0.909f * x1v / (1.f + __expf(-x1v)), n1, m);
      scat(wAA, 0.909f * x2v / (1.f + __expf(-x2v)), n0, m);
      scat(wAA, 0.909f * x3v / (1.f + __expf(-x3v)), n1, m);
    }
    __syncthreads();

    // ---- stage 3: f = u@Wf2 + bf2, g = w2@Wg2 + bg2 ----
    f32x4 fc0 = (f32x4){0.f,0.f,0.f,0.f}, fc1 = fc0, gc0 = fc0, gc1 = fc0;
#pragma unroll
    for (int s = 0; s < 8; ++s) {
      bf16x8 a1 = uAv[s * 64 + lane];
      bf16x8 a2 = wAv[s * 64 + lane];
      fc0 = MFMA16(a1, pWf2[(s * 16 + 2 * w    ) * 64 + lane], fc0);
      fc1 = MFMA16(a1, pWf2[(s * 16 + 2 * w + 1) * 64 + lane], fc1);
      gc0 = MFMA16(a2, pWg2[(s * 16 + 2 * w    ) * 64 + lane], gc0);
      gc1 = MFMA16(a2, pWg2[(s * 16 + 2 * w + 1) * 64 + lane], gc1);
    }

    // ---- Euler-Maruyama update (fp32 state in regs) ----
#pragma unroll
    for (int r = 0; r < 4; ++r) {
      int m = q4 * 4 + r;
      float f0 = fc0[r] + bf2v0, f1 = fc1[r] + bf2v1;
      float g0 = gc0[r] + bg2v0, g1 = gc1[r] + bg2v1;
      float y0n = yr[0][r] + f0 * dtv + g0 * (sdt * ep[0][r]);
      float y1n = yr[1][r] + f1 * dtv + g1 * (sdt * ep[1][r]);
      yr[0][r] = y0n; yr[1][r] = y1n;
      if (st + 1 == lst[r]) { zfin[m * H + n0] = y0n; zfin[m * H + n1] = y1n; }
      scat(yA, y0n, n0, m);
      scat(yA, y1n, n1, m);
    }
    __syncthreads();

    // ---- pred[:, st+1, :] = y_new @ Wd^T + bd (waves 0-3) ----
    if (w < 4) {
      f32x4 acc = (f32x4){0.f, 0.f, 0.f, 0.f};
#pragma unroll
      for (int s = 0; s < 8; ++s)
        acc = MFMA16(yAv[s * 64 + lane], pWd[(s * 4 + w) * 64 + lane], acc);
#pragma unroll
      for (int r = 0; r < 4; ++r) {
        int m = q4 * 4 + r;
        pred[((size_t)(rb + m) * T + st + 1) * 64 + np] = acc[r] + bdv;
      }
    }
  }

  // ---- logits = z_final @ Wc^T + bc (fp32, one-time) ----
  __syncthreads();
  if (tid < BT * NC) {
    int m = tid / NC, cc = tid - m * NC;
    float acc = bc[cc];
#pragma unroll 8
    for (int k = 0; k < H; ++k) acc += zfin[m * H + k] * Wc[cc * H + k];
    logits[(rb + m) * NC + cc] = acc;
  }
}

extern "C" void kernel_launch(void* const* d_in, const int* in_sizes, int n_in,
                              void* d_out, int out_size, void* d_ws, size_t ws_size,
                              hipStream_t stream) {
  const float* coeffs = (const float*)d_in[0];
  const float* times  = (const float*)d_in[1];
  const int*   mask   = (const int*)d_in[2];
  const float* noise  = (const float*)d_in[3];
  const float* W_in   = (const float*)d_in[4];
  const float* b_in   = (const float*)d_in[5];
  const float* Wf1    = (const float*)d_in[6];
  const float* bf1    = (const float*)d_in[7];
  const float* Wf2    = (const float*)d_in[8];
  const float* bf2    = (const float*)d_in[9];
  const float* Wn     = (const float*)d_in[10];
  const float* bn     = (const float*)d_in[11];
  const float* Wg1    = (const float*)d_in[12];
  const float* bg1    = (const float*)d_in[13];
  const float* Wg2    = (const float*)d_in[14];
  const float* bg2    = (const float*)d_in[15];
  const float* W0     = (const float*)d_in[16];
  const float* b0p    = (const float*)d_in[17];
  const float* Wd     = (const float*)d_in[18];
  const float* bd     = (const float*)d_in[19];
  const float* Wc     = (const float*)d_in[20];
  const float* bc     = (const float*)d_in[21];

  unsigned short* wpack = (unsigned short*)d_ws;   // 800 KB
  float* out    = (float*)d_out;
  float* pred   = out;                             // (B, T, 64)
  float* logits = out + (size_t)B * T * 64;        // (B, 10)

  hipLaunchKernelGGL(pack_frags, dim3((TOTAL_PK + 255) / 256), dim3(256), 0, stream,
                     W_in, Wn, Wf1, Wg1, Wf2, Wg2, Wd, wpack);
  hipLaunchKernelGGL(sde_mfma, dim3(NWG), dim3(512), 0, stream,
                     coeffs, times, mask, noise, b_in, bf1, bf2, bn, bg1, bg2,
                     W_in, Wn, W0, b0p, bd, Wc, bc, wpack, pred, logits);
}